// Round 12
// baseline (185.383 us; speedup 1.0000x reference)
//
#include <hip/hip_runtime.h>

using int32x4 = __attribute__((ext_vector_type(4))) int;

#define BM 256
#define BN 256
#define TBUF 32768   // one K-tile buffer: A(16K) + B(16K); K-tile = 64 bytes of K

// ---------------------------------------------------------------------------
// Kernel 1: pack int32 activations -> int8 (values in [-128,127])
// ---------------------------------------------------------------------------
__global__ __launch_bounds__(256) void pack_x_kernel(const int32x4* __restrict__ x,
                                                     int32x4* __restrict__ xp,
                                                     int nvec) {
    int t = blockIdx.x * 256 + threadIdx.x;
    if (t >= nvec) return;
    int32x4 a = x[t * 4 + 0];
    int32x4 b = x[t * 4 + 1];
    int32x4 c = x[t * 4 + 2];
    int32x4 d = x[t * 4 + 3];
    int32x4 o;
    o.x = (a.x & 255) | ((a.y & 255) << 8) | ((a.z & 255) << 16) | (a.w << 24);
    o.y = (b.x & 255) | ((b.y & 255) << 8) | ((b.z & 255) << 16) | (b.w << 24);
    o.z = (c.x & 255) | ((c.y & 255) << 8) | ((c.z & 255) << 16) | (c.w << 24);
    o.w = (d.x & 255) | ((d.y & 255) << 8) | ((d.z & 255) << 16) | (d.w << 24);
    xp[t] = o;
}

// ---------------------------------------------------------------------------
// Kernel 2: weight transform — int32 [K][N] -> int8 [N][K]
// ---------------------------------------------------------------------------
__global__ __launch_bounds__(256) void transform_w_kernel(const int* __restrict__ w,
                                                          unsigned char* __restrict__ wt,
                                                          int K, int N) {
    __shared__ unsigned char tileT[64][72];
    int tx = threadIdx.x & 15;
    int ty = threadIdx.x >> 4;
    int n0 = blockIdx.x * 64;
    int k0 = blockIdx.y * 64;
#pragma unroll
    for (int r = 0; r < 4; ++r) {
        int row = ty * 4 + r;  // k_local
        int32x4 v = *(const int32x4*)&w[(size_t)(k0 + row) * N + n0 + tx * 4];
        tileT[tx * 4 + 0][row] = (unsigned char)(v.x & 255);
        tileT[tx * 4 + 1][row] = (unsigned char)(v.y & 255);
        tileT[tx * 4 + 2][row] = (unsigned char)(v.z & 255);
        tileT[tx * 4 + 3][row] = (unsigned char)(v.w & 255);
    }
    __syncthreads();
#pragma unroll
    for (int r = 0; r < 4; ++r) {
        int row = ty * 4 + r;  // n_local
        uchar4 v = *(const uchar4*)&tileT[row][tx * 4];
        *(uchar4*)&wt[(size_t)(n0 + row) * K + k0 + tx * 4] = v;
    }
}

// ---------------------------------------------------------------------------
// Kernel 3: int8 GEMM, 256x256 tile, 16 waves (4x4 grid, 64x64 output each ->
// acc=64 regs -> 4 waves/SIMD occupancy: TLP overlaps DS and MFMA pipes).
// 16x16x64 MFMA, verified 0-conflict fragment family + XOR swizzle, GLL
// staging, 4-deep LDS ring, wave-exact counted-vmcnt ledger, 1 barrier/tile.
// ---------------------------------------------------------------------------
__global__ __launch_bounds__(1024, 4) void gemm_i8_w16(
    const char* __restrict__ A,   // [M][K] int8
    const char* __restrict__ Bt,  // [N][K] int8
    const int* __restrict__ bias,
    const int* __restrict__ shiftp,
    int* __restrict__ C,          // [M][N]
    int M, int N, int K) {
    __shared__ char smem[4 * TBUF];  // 128 KiB

    const int nbn = N / BN;
    const int nwg = gridDim.x;
    const int bid = blockIdx.x;
    const int cpx = nwg >> 3;  // nwg % 8 == 0 -> bijective XCD swizzle
    const int swz = (bid & 7) * cpx + (bid >> 3);
    const int m0 = (swz / nbn) * BM;
    const int n0 = (swz % nbn) * BN;

    const int t = threadIdx.x;   // 0..1023
    const int lane = t & 63;
    const int wave = t >> 6;     // 0..15
    const int wrow = wave >> 2;  // 0..3  (M quarter, 64 rows)
    const int wcol = wave & 3;   // 0..3  (N quarter, 64 cols)

    // ---- staging geometry (pre-swizzled global source, linear LDS dest) ----
    // 1024 threads x 16B = 16 KiB per GLL = all 256 rows x 64B of one matrix.
    const int s_row = t >> 2;                                  // 0..255
    const int s_col = ((t & 3) << 4) ^ (((t >> 3) & 3) << 4);  // xor(row bits 1-2)
    const char* a_src = A + (size_t)(m0 + s_row) * K + s_col;
    const char* b_src = Bt + (size_t)(n0 + s_row) * K + s_col;
    char* lds_st = smem + t * 16;

    // ---- fragment-read geometry (verified 16-rows x 4-col-groups family) ----
    const int lr = lane & 15;
    const int lc = (lane >> 4) << 4;
    const int xr = ((lr >> 1) & 3) << 4;
    const int a_off = ((wrow << 6) + lr) * 64 + (lc ^ xr);          // + mf*1024
    const int b_off = 16384 + ((wcol << 6) + lr) * 64 + (lc ^ xr);  // + nf*1024

    int32x4 acc[4][4] = {};
    int32x4 af[4], bf[4];

    const int nt = K / 64;  // 64 K-tiles (>= 4)

#define GLL(src, dst)                                                 \
    __builtin_amdgcn_global_load_lds(                                 \
        (const __attribute__((address_space(1))) void*)(src),        \
        (__attribute__((address_space(3))) void*)(dst), 16, 0, 0)

#define FENCE asm volatile("" ::: "memory")
#define BARR                           \
    do {                               \
        FENCE;                         \
        __builtin_amdgcn_s_barrier();  \
        FENCE;                         \
    } while (0)
#define SB0 __builtin_amdgcn_sched_barrier(0)
#define LGKM0                                                   \
    do {                                                        \
        asm volatile("s_waitcnt lgkmcnt(0)" ::: "memory");      \
        SB0;                                                    \
    } while (0)
#define VMW(n)                                                  \
    do {                                                        \
        asm volatile("s_waitcnt vmcnt(" #n ")" ::: "memory");   \
        SB0;                                                    \
    } while (0)

    // stage K-tile TT into ring slot (TT&3): 2 GLL (A 16K, B 16K)
#define STAGE(TT)                                                         \
    do {                                                                  \
        const int sb_ = ((TT) & 3) * TBUF;                                \
        const size_t kc_ = (size_t)(TT) * 64;                             \
        GLL(a_src + kc_, lds_st + sb_);                                   \
        GLL(b_src + kc_, lds_st + sb_ + 16384);                           \
    } while (0)

    // One K-tile. Entry: buf(TT) published (drained by prev tile's VMW + BARR).
#define TILE(TT, DOSTAGE, WTAIL, DOBARR)                                           \
    do {                                                                           \
        const int base_ = ((TT) & 3) * TBUF;                                       \
        _Pragma("unroll") for (int i = 0; i < 4; ++i)                              \
            af[i] = *(const int32x4*)&smem[base_ + a_off + i * 1024];              \
        _Pragma("unroll") for (int i = 0; i < 4; ++i)                              \
            bf[i] = *(const int32x4*)&smem[base_ + b_off + i * 1024];              \
        if (DOSTAGE) STAGE((TT) + 3);                                              \
        LGKM0;                                                                     \
        __builtin_amdgcn_s_setprio(1);                                             \
        _Pragma("unroll") for (int mi = 0; mi < 4; ++mi)                           \
            _Pragma("unroll") for (int ni = 0; ni < 4; ++ni)                       \
                acc[mi][ni] = __builtin_amdgcn_mfma_i32_16x16x64_i8(               \
                    af[mi], bf[ni], acc[mi][ni], 0, 0, 0);                         \
        __builtin_amdgcn_s_setprio(0);                                             \
        WTAIL;                                                                     \
        if (DOBARR) BARR;                                                          \
    } while (0)

    // ---- prologue: stage tiles 0,1,2 into slots 0,1,2 ----
    STAGE(0);
    STAGE(1);
    STAGE(2);
    VMW(4);  // own stage(0) (oldest 2) done; stage(1),(2) in flight
    BARR;    // stage(0) published

    // ---- main loop ----
    // Steady tile t: reads buf(t); stages t+3; VMW(4) drains stage(t+1)
    // (issued 2 tiles ago, ~2500+ cyc — HBM latency fully covered); BARR
    // publishes stage(t+1) and licenses slot (t+3)&3 overwrite next tile.
    int tt = 0;
    for (; tt < nt - 3; ++tt) TILE(tt, 1, VMW(4), 1);
    TILE(nt - 3, 0, VMW(2), 1);   // drains stage(nt-2); leaves stage(nt-1)
    TILE(nt - 2, 0, VMW(0), 1);   // drains stage(nt-1)
    TILE(nt - 1, 0, (void)0, 0);  // last tile

    // ---- epilogue: bias + shift, int32 store (16x16 C/D layout) ----
    const int s = *shiftp;
    const int crow = (lane >> 4) << 2;
    const int ccol = lane & 15;
    int bv[4];
#pragma unroll
    for (int nf = 0; nf < 4; ++nf) bv[nf] = bias[n0 + wcol * 64 + nf * 16 + ccol];
#pragma unroll
    for (int mf = 0; mf < 4; ++mf) {
        const int grow0 = m0 + wrow * 64 + mf * 16 + crow;
#pragma unroll
        for (int nf = 0; nf < 4; ++nf) {
            const int gcol = n0 + wcol * 64 + nf * 16 + ccol;
#pragma unroll
            for (int r = 0; r < 4; ++r) {
                int y = acc[mf][nf][r] + bv[nf];
                y = (s > 0) ? (y >> s) : y;
                C[(size_t)(grow0 + r) * N + gcol] = y;
            }
        }
    }
#undef GLL
#undef FENCE
#undef BARR
#undef SB0
#undef LGKM0
#undef VMW
#undef STAGE
#undef TILE
}

// ---------------------------------------------------------------------------
extern "C" void kernel_launch(void* const* d_in, const int* in_sizes, int n_in,
                              void* d_out, int out_size, void* d_ws, size_t ws_size,
                              hipStream_t stream) {
    const int* x = (const int*)d_in[0];
    const int* w = (const int*)d_in[1];   // int8 values stored as int32
    const int* bias = (const int*)d_in[2];
    const int* shiftp = (const int*)d_in[3];
    int* out = (int*)d_out;

    const int N = in_sizes[2];      // 4096
    const int K = in_sizes[1] / N;  // 4096
    const int M = in_sizes[0] / K;  // 8192

    char* xp = (char*)d_ws;
    unsigned char* wt = (unsigned char*)d_ws + (size_t)M * K;

    int nvec = (int)(((long long)M * K) / 16);
    pack_x_kernel<<<(nvec + 255) / 256, 256, 0, stream>>>((const int32x4*)x, (int32x4*)xp, nvec);

    dim3 tgrid(N / 64, K / 64);
    transform_w_kernel<<<tgrid, 256, 0, stream>>>(w, wt, K, N);

    int nwg = (M / BM) * (N / BN);  // 512, %8==0
    gemm_i8_w16<<<nwg, 1024, 0, stream>>>(xp, (const char*)wt, bias, shiftp, out, M, N, K);
}